// Round 14
// baseline (121.927 us; speedup 1.0000x reference)
//
#include <hip/hip_runtime.h>
#include <hip/hip_bf16.h>

// Problem dims (fixed by reference)
#define B_  2
#define LQ_ 1024
#define LK_ 10000
#define E_  256
#define H_  8
#define D_  32
#define NT_ ((LK_ + 63) / 64)  // 157

typedef __attribute__((ext_vector_type(8))) short bf16x8;
typedef __attribute__((ext_vector_type(4))) short bf16x4;
typedef __attribute__((ext_vector_type(4))) float f32x4;

#define LOG2E 1.4426950408889634f

// float -> bf16 via native cast (compiler pairs into v_cvt_pk_bf16_f32)
static __device__ __forceinline__ short bfc(float x) {
  __bf16 b = (__bf16)x;
  return __builtin_bit_cast(short, b);
}
static __device__ __forceinline__ float bf2f(short s) {
  return (float)__builtin_bit_cast(__bf16, s);
}

// fast exp2 (v_exp_f32). NOTE: __exp2f collides with a glibc identifier.
#if __has_builtin(__builtin_amdgcn_exp2f)
static __device__ __forceinline__ float ex2(float x) {
  return __builtin_amdgcn_exp2f(x);
}
#else
static __device__ __forceinline__ float ex2(float x) { return exp2f(x); }
#endif

#if __has_builtin(__builtin_amdgcn_mfma_f32_16x16x16bf16_1k)
static __device__ __forceinline__ f32x4 mfma_pv(bf16x4 a, bf16x4 b, f32x4 c) {
  return __builtin_amdgcn_mfma_f32_16x16x16bf16_1k(a, b, c, 0, 0, 0);
}
#else
static __device__ __forceinline__ f32x4 mfma_pv(bf16x4 a, bf16x4 b, f32x4 c) {
  asm volatile("s_nop 1\n\tv_mfma_f32_16x16x16_bf16 %0, %1, %2, %0"
               : "+v"(c) : "v"(a), "v"(b));
  return c;
}
#endif

// Tile barrier WITHOUT vmcnt drain [T4]: cross-wave hazard at the tile
// boundary is LDS-only. Global prefetch loads only feed registers, so they
// stay in flight across the barrier (R12: +21 us vs __syncthreads).
static __device__ __forceinline__ void tile_barrier() {
  __builtin_amdgcn_sched_barrier(0);
  asm volatile("s_waitcnt lgkmcnt(0)" ::: "memory");
  __builtin_amdgcn_s_barrier();
  __builtin_amdgcn_sched_barrier(0);
}

// m204 bijective XCD-chunked swizzle
static __device__ __forceinline__ int xcd_swizzle(int flat, int nwg) {
  const int xcd = flat & 7, rest = flat >> 3;
  const int q = nwg >> 3, r = nwg & 7;
  return (xcd < r ? xcd * (q + 1) : r * (q + 1) + (xcd - r) * q) + rest;
}

// split f32x8 (two float4) into hi/lo bf16x8 planes
static __device__ __forceinline__ void split8(const float4& a, const float4& b,
                                              bf16x8& hi, bf16x8& lo) {
  float v[8] = {a.x, a.y, a.z, a.w, b.x, b.y, b.z, b.w};
#pragma unroll
  for (int i = 0; i < 8; ++i) {
    const short h = bfc(v[i]);
    hi[i] = h;
    lo[i] = bfc(v[i] - bf2f(h));
  }
}

// ---------------------------------------------------------------------------
// wtrans4: Wt_bf16[n][k] = bf16(W[k][n]) for 4 weights in one launch.
// ---------------------------------------------------------------------------
__global__ __launch_bounds__(256) void wtrans4(
    const float* __restrict__ W0, const float* __restrict__ W1,
    const float* __restrict__ W2, const float* __restrict__ W3,
    unsigned short* __restrict__ T0, unsigned short* __restrict__ T1,
    unsigned short* __restrict__ T2, unsigned short* __restrict__ T3) {
  const float* W;
  unsigned short* T;
  switch (blockIdx.z) {
    case 0:  W = W0; T = T0; break;
    case 1:  W = W1; T = T1; break;
    case 2:  W = W2; T = T2; break;
    default: W = W3; T = T3; break;
  }
  __shared__ float ts[16][17];
  const int tx = threadIdx.x & 15;
  const int ty = threadIdx.x >> 4;
  const int k0 = blockIdx.x * 16;
  const int n0 = blockIdx.y * 16;
  ts[ty][tx] = W[(size_t)(k0 + ty) * 256 + n0 + tx];
  __syncthreads();
  T[(size_t)(n0 + ty) * 256 + k0 + tx] = (unsigned short)bfc(ts[tx][ty]);
}

// ---------------------------------------------------------------------------
// proj_wave<KV,F32OUT>: barrier-free, LDS-free projection GEMM (R12 struct —
// 32 rows/wave; R13's 16-row variant halved MFMA-per-W-load and regressed).
// Wave owns 32(m)x64(n); A from global f32 split hi/lo in regs; W from
// L2-resident bf16 Wt[n][k]. mfma(W_frag, A_frag) -> vectorized stores.
// ---------------------------------------------------------------------------
template <bool KV, bool F32OUT>
__global__ __launch_bounds__(256) void proj_wave(
    const float* __restrict__ A,
    const unsigned short* __restrict__ Wt1,
    const unsigned short* __restrict__ Wt2,
    const float* __restrict__ b1, const float* __restrict__ b2,
    void* __restrict__ C1v, void* __restrict__ C2v) {
  const int lane = threadIdx.x & 63;
  const int nt   = threadIdx.x >> 6;   // wave id = n-tile (0..3)
  const int mt   = blockIdx.x;
  const int lr   = lane & 15;
  const int oc   = lane >> 4;          // k-octet (0..3)
  const int m0   = mt * 32;
  const int n0   = nt * 64;

  f32x4 ac1[2][4];
  f32x4 ac2[2][4];
#pragma unroll
  for (int s = 0; s < 2; ++s)
#pragma unroll
    for (int q = 0; q < 4; ++q) {
      ac1[s][q] = (f32x4){0.f, 0.f, 0.f, 0.f};
      if (KV) ac2[s][q] = (f32x4){0.f, 0.f, 0.f, 0.f};
    }

  const float* a0p = &A[(size_t)(m0 + lr) * 256 + oc * 8];
  const float* a1p = a0p + 16 * 256;

  float4 c0a = *(const float4*)(a0p + 0);
  float4 c0b = *(const float4*)(a0p + 4);
  float4 c1a = *(const float4*)(a1p + 0);
  float4 c1b = *(const float4*)(a1p + 4);

  for (int kb = 0; kb < 8; ++kb) {
    bf16x8 ah0, al0, ah1, al1;
    split8(c0a, c0b, ah0, al0);
    split8(c1a, c1b, ah1, al1);

    const size_t wko = (size_t)(kb * 32 + oc * 8);
    bf16x8 w1[4], w2[4];
#pragma unroll
    for (int q = 0; q < 4; ++q) {
      w1[q] = *(const bf16x8*)&Wt1[(size_t)(n0 + q * 16 + lr) * 256 + wko];
      if (KV) w2[q] = *(const bf16x8*)&Wt2[(size_t)(n0 + q * 16 + lr) * 256 + wko];
    }

    if (kb < 7) {
      c0a = *(const float4*)(a0p + (kb + 1) * 32 + 0);
      c0b = *(const float4*)(a0p + (kb + 1) * 32 + 4);
      c1a = *(const float4*)(a1p + (kb + 1) * 32 + 0);
      c1b = *(const float4*)(a1p + (kb + 1) * 32 + 4);
    }

#pragma unroll
    for (int q = 0; q < 4; ++q) {
      ac1[0][q] = __builtin_amdgcn_mfma_f32_16x16x32_bf16(w1[q], ah0, ac1[0][q], 0, 0, 0);
      ac1[0][q] = __builtin_amdgcn_mfma_f32_16x16x32_bf16(w1[q], al0, ac1[0][q], 0, 0, 0);
      ac1[1][q] = __builtin_amdgcn_mfma_f32_16x16x32_bf16(w1[q], ah1, ac1[1][q], 0, 0, 0);
      ac1[1][q] = __builtin_amdgcn_mfma_f32_16x16x32_bf16(w1[q], al1, ac1[1][q], 0, 0, 0);
      if (KV) {
        ac2[0][q] = __builtin_amdgcn_mfma_f32_16x16x32_bf16(w2[q], ah0, ac2[0][q], 0, 0, 0);
        ac2[1][q] = __builtin_amdgcn_mfma_f32_16x16x32_bf16(w2[q], ah1, ac2[1][q], 0, 0, 0);
      }
    }
  }

#pragma unroll
  for (int s = 0; s < 2; ++s) {
#pragma unroll
    for (int q = 0; q < 4; ++q) {
      const int m = m0 + s * 16 + lr;
      const int n = n0 + q * 16 + oc * 4;
      const float4 bv1 = *(const float4*)&b1[n];
      if (F32OUT) {
        float4 o;
        o.x = ac1[s][q][0] + bv1.x; o.y = ac1[s][q][1] + bv1.y;
        o.z = ac1[s][q][2] + bv1.z; o.w = ac1[s][q][3] + bv1.w;
        *(float4*)&((float*)C1v)[(size_t)m * 256 + n] = o;
      } else {
        ushort4 o;
        o.x = (unsigned short)bfc(ac1[s][q][0] + bv1.x);
        o.y = (unsigned short)bfc(ac1[s][q][1] + bv1.y);
        o.z = (unsigned short)bfc(ac1[s][q][2] + bv1.z);
        o.w = (unsigned short)bfc(ac1[s][q][3] + bv1.w);
        *(ushort4*)&((unsigned short*)C1v)[(size_t)m * 256 + n] = o;
      }
      if (KV) {
        const float4 bv2 = *(const float4*)&b2[n];
        ushort4 o;
        o.x = (unsigned short)bfc(ac2[s][q][0] + bv2.x);
        o.y = (unsigned short)bfc(ac2[s][q][1] + bv2.y);
        o.z = (unsigned short)bfc(ac2[s][q][2] + bv2.z);
        o.w = (unsigned short)bfc(ac2[s][q][3] + bv2.w);
        *(ushort4*)&((unsigned short*)C2v)[(size_t)m * 256 + n] = o;
      }
    }
  }
}

// ---------------------------------------------------------------------------
// attn_mfma: 128 q-rows/block, 32 q-rows/wave (two 16-row fragments A,B).
// Fixed-base softmax; l-accumulation in f32x4 (4x ILP — the scalar l += e
// was a 32-deep serial fadd chain per tile); T4 lgkmcnt-only tile barrier;
// 2-phase LDS dbuf; split partials combine by plain sum.
// ---------------------------------------------------------------------------
__global__ __launch_bounds__(256, 4) void attn_mfma(const float* __restrict__ q,
                                                    const unsigned short* __restrict__ kbf,
                                                    const unsigned short* __restrict__ vbf,
                                                    float* __restrict__ Opart,
                                                    float* __restrict__ lpart,
                                                    float* __restrict__ o_direct,
                                                    int tiles_per_split, int nsplit) {
  const int nwg = 64 * gridDim.z;
  const int l   = xcd_swizzle(blockIdx.x + 8 * (blockIdx.y + 8 * blockIdx.z), nwg);
  const int qb   = l & 7;
  const int h    = (l >> 3) & 7;
  const int z    = l >> 6;
  const int s_id = z / B_;
  const int b    = z % B_;
  const int t    = threadIdx.x;
  const int lane = t & 63;
  const int w    = t >> 6;
  const int lq   = lane & 15;
  const int grp  = lane >> 4;

  __shared__ ushort Klds[2][64][64];
  __shared__ ushort Vtld[2][32][64];

  const int t0 = s_id * tiles_per_split;
  const int t1 = min(NT_, t0 + tiles_per_split);

  const int qrowA = qb * 128 + w * 32 + lq;  // fragment A rows
  const int qrowB = qrowA + 16;              // fragment B rows
  bf16x8 qfA, qfB;
  {
    const float* qpA = &q[((size_t)(b * LQ_ + qrowA)) * E_ + h * D_ + grp * 8];
    const float* qpB = &q[((size_t)(b * LQ_ + qrowB)) * E_ + h * D_ + grp * 8];
    const float4 a0 = *(const float4*)qpA;
    const float4 a1 = *(const float4*)(qpA + 4);
    const float4 b0 = *(const float4*)qpB;
    const float4 b1 = *(const float4*)(qpB + 4);
    qfA[0] = bfc(a0.x * LOG2E); qfA[1] = bfc(a0.y * LOG2E);
    qfA[2] = bfc(a0.z * LOG2E); qfA[3] = bfc(a0.w * LOG2E);
    qfA[4] = bfc(a1.x * LOG2E); qfA[5] = bfc(a1.y * LOG2E);
    qfA[6] = bfc(a1.z * LOG2E); qfA[7] = bfc(a1.w * LOG2E);
    qfB[0] = bfc(b0.x * LOG2E); qfB[1] = bfc(b0.y * LOG2E);
    qfB[2] = bfc(b0.z * LOG2E); qfB[3] = bfc(b0.w * LOG2E);
    qfB[4] = bfc(b1.x * LOG2E); qfB[5] = bfc(b1.y * LOG2E);
    qfB[6] = bfc(b1.z * LOG2E); qfB[7] = bfc(b1.w * LOG2E);
  }

  const int krow_l = t >> 2;
  const int kchunk = t & 3;
  const int vkp    = t >> 3;
  const int vd     = (t & 7) * 4;

  f32x4 lAv = {0.f, 0.f, 0.f, 0.f}, lBv = {0.f, 0.f, 0.f, 0.f};
  f32x4 a0A = {0.f, 0.f, 0.f, 0.f}, a1A = {0.f, 0.f, 0.f, 0.f};
  f32x4 a0B = {0.f, 0.f, 0.f, 0.f}, a1B = {0.f, 0.f, 0.f, 0.f};

  const size_t kvrow0 = (size_t)b * LK_;

  uint4 kval; ushort4 v0, v1;
  auto load_tile = [&](int kn) {
    if (kn == NT_ - 1) {
      const int krow  = min(kn * 64 + krow_l, LK_ - 1);
      const int vrow0 = min(kn * 64 + 2 * vkp, LK_ - 1);
      const int vrow1 = min(kn * 64 + 2 * vkp + 1, LK_ - 1);
      kval = *(const uint4*)&kbf[(kvrow0 + krow) * E_ + h * D_ + kchunk * 8];
      v0 = *(const ushort4*)&vbf[(kvrow0 + vrow0) * E_ + h * D_ + vd];
      v1 = *(const ushort4*)&vbf[(kvrow0 + vrow1) * E_ + h * D_ + vd];
    } else {
      kval = *(const uint4*)&kbf[(kvrow0 + kn * 64 + krow_l) * E_ + h * D_ + kchunk * 8];
      v0 = *(const ushort4*)&vbf[(kvrow0 + kn * 64 + 2 * vkp) * E_ + h * D_ + vd];
      v1 = *(const ushort4*)&vbf[(kvrow0 + kn * 64 + 2 * vkp + 1) * E_ + h * D_ + vd];
    }
  };
  auto store_tile = [&](int buf) {
    *(uint4*)((char*)&Klds[buf][krow_l][0] + ((kchunk * 16) ^ ((krow_l & 7) << 4))) = kval;
#pragma unroll
    for (int i = 0; i < 4; ++i) {
      const int d = vd + i;
      *(ushort2*)((char*)&Vtld[buf][d][0] + ((vkp * 4) ^ ((d & 7) << 4))) =
          make_ushort2(((const unsigned short*)&v0)[i], ((const unsigned short*)&v1)[i]);
    }
  };

  load_tile(t0);
  store_tile(0);
  if (t0 + 1 < t1) load_tile(t0 + 1);
  tile_barrier();

  int cur = 0;
  for (int kt = t0; kt < t1; ++kt) {
    const int rem = LK_ - kt * 64;

    if (kt + 1 < t1) store_tile(cur ^ 1);
    if (kt + 2 < t1) load_tile(kt + 2);

    // S^T = K · Q^T for both q-fragments (kf shared)
    f32x4 pA[4], pB[4];
    __builtin_amdgcn_s_setprio(1);
#pragma unroll
    for (int s = 0; s < 4; ++s) {
      const int row = s * 16 + lq;
      const bf16x8 kf = *(const bf16x8*)((const char*)&Klds[cur][row][0] +
                                         ((grp * 16) ^ ((row & 7) << 4)));
      const f32x4 zero = {0.f, 0.f, 0.f, 0.f};
      pA[s] = __builtin_amdgcn_mfma_f32_16x16x32_bf16(kf, qfA, zero, 0, 0, 0);
      pB[s] = __builtin_amdgcn_mfma_f32_16x16x32_bf16(kf, qfB, zero, 0, 0, 0);
    }
    __builtin_amdgcn_s_setprio(0);

    // fixed-base softmax: e = 2^s directly (q pre-scaled by log2e).
    // l accumulated per-r (f32x4) — independent add chains, 4x ILP.
    bf16x4 pbA[4], pbB[4];
    if (rem >= 64) {
#pragma unroll
      for (int s = 0; s < 4; ++s)
#pragma unroll
        for (int r = 0; r < 4; ++r) {
          const float eA = ex2(pA[s][r]);
          const float eB = ex2(pB[s][r]);
          lAv[r] += eA; lBv[r] += eB;
          pbA[s][r] = bfc(eA); pbB[s][r] = bfc(eB);
        }
    } else {
#pragma unroll
      for (int s = 0; s < 4; ++s) {
        const bool vs = (s * 16 + grp * 4) < rem;
#pragma unroll
        for (int r = 0; r < 4; ++r) {
          const float eA = vs ? ex2(pA[s][r]) : 0.f;
          const float eB = vs ? ex2(pB[s][r]) : 0.f;
          lAv[r] += eA; lBv[r] += eB;
          pbA[s][r] = bfc(eA); pbB[s][r] = bfc(eB);
        }
      }
    }

    // O^T += V^T · P for both fragments (vf shared)
    __builtin_amdgcn_s_setprio(1);
#pragma unroll
    for (int s = 0; s < 4; ++s) {
      {
        const int row = lq;
        const bf16x4 vf = *(const bf16x4*)((const char*)&Vtld[cur][row][0] +
                                           ((s * 32 + grp * 8) ^ ((row & 7) << 4)));
        a0A = mfma_pv(vf, pbA[s], a0A);
        a0B = mfma_pv(vf, pbB[s], a0B);
      }
      {
        const int row = 16 + lq;
        const bf16x4 vf = *(const bf16x4*)((const char*)&Vtld[cur][row][0] +
                                           ((s * 32 + grp * 8) ^ ((row & 7) << 4)));
        a1A = mfma_pv(vf, pbA[s], a1A);
        a1B = mfma_pv(vf, pbB[s], a1B);
      }
    }
    __builtin_amdgcn_s_setprio(0);

    tile_barrier();
    cur ^= 1;
  }

  float lA = (lAv[0] + lAv[1]) + (lAv[2] + lAv[3]);
  float lB = (lBv[0] + lBv[1]) + (lBv[2] + lBv[3]);
  lA += __shfl_xor(lA, 16);
  lA += __shfl_xor(lA, 32);
  lB += __shfl_xor(lB, 16);
  lB += __shfl_xor(lB, 32);

  if (nsplit == 1) {
    const float invA = 1.f / lA;
    const float invB = 1.f / lB;
    float* opA = &o_direct[((size_t)(b * LQ_ + qrowA)) * E_ + h * D_];
    float* opB = &o_direct[((size_t)(b * LQ_ + qrowB)) * E_ + h * D_];
#pragma unroll
    for (int r = 0; r < 4; ++r) {
      opA[grp * 4 + r]      = a0A[r] * invA;
      opA[16 + grp * 4 + r] = a1A[r] * invA;
      opB[grp * 4 + r]      = a0B[r] * invB;
      opB[16 + grp * 4 + r] = a1B[r] * invB;
    }
  } else {
    const size_t pbA =
        (size_t)s_id * (B_ * H_ * LQ_) + ((size_t)b * H_ + h) * LQ_ + qrowA;
    const size_t pbB = pbA + 16;
#pragma unroll
    for (int r = 0; r < 4; ++r) {
      Opart[pbA * D_ + grp * 4 + r]      = a0A[r];
      Opart[pbA * D_ + 16 + grp * 4 + r] = a1A[r];
      Opart[pbB * D_ + grp * 4 + r]      = a0B[r];
      Opart[pbB * D_ + 16 + grp * 4 + r] = a1B[r];
    }
    if (grp == 0) {
      lpart[pbA] = lA;
      lpart[pbB] = lB;
    }
  }
}

// ---------------------------------------------------------------------------
// attn_merge: absolute-scale partials combine by plain sum.
// ---------------------------------------------------------------------------
__global__ __launch_bounds__(256) void attn_merge(const float* __restrict__ Opart,
                                                  const float* __restrict__ lpart,
                                                  float* __restrict__ o, int S) {
  const int idx = blockIdx.x * 256 + threadIdx.x;
  if (idx >= B_ * LQ_ * E_) return;
  const int e   = idx & (E_ - 1);
  const int row = idx >> 8;
  const int b   = row >> 10;
  const int qq  = row & (LQ_ - 1);
  const int h   = e >> 5;
  const int d   = e & (D_ - 1);
  const size_t base   = ((size_t)b * H_ + h) * LQ_ + qq;
  const size_t stride = (size_t)B_ * H_ * LQ_;

  float lsum = 0.f, osum = 0.f;
  for (int s = 0; s < S; ++s) {
    lsum += lpart[s * stride + base];
    osum += Opart[(s * stride + base) * D_ + d];
  }
  o[idx] = osum / lsum;
}

// ---------------------------------------------------------------------------
extern "C" void kernel_launch(void* const* d_in, const int* in_sizes, int n_in,
                              void* d_out, int out_size, void* d_ws, size_t ws_size,
                              hipStream_t stream) {
  const float* bev     = (const float*)d_in[0];
  const float* queries = (const float*)d_in[1];
  const float* Wq      = (const float*)d_in[2];
  const float* bq      = (const float*)d_in[3];
  const float* Wk      = (const float*)d_in[4];
  const float* bk      = (const float*)d_in[5];
  const float* Wv      = (const float*)d_in[6];
  const float* bv      = (const float*)d_in[7];
  const float* Wo      = (const float*)d_in[8];
  const float* bo      = (const float*)d_in[9];
  float* out = (float*)d_out;

  // ws: q f32 | k bf16 | v bf16 | o f32 | Wtq|Wtk|Wtv|Wto bf16 | Opart | l
  const size_t nq = (size_t)B_ * LQ_ * E_;  // 524288
  const size_t nk = (size_t)B_ * LK_ * E_;  // 5120000
  const size_t nw = (size_t)E_ * E_;        // 65536
  float*          qws = (float*)d_ws;
  unsigned short* kbf = (unsigned short*)(qws + nq);
  unsigned short* vbf = kbf + nk;
  float*          ows = (float*)(vbf + nk);
  unsigned short* Wtq = (unsigned short*)(ows + nq);
  unsigned short* Wtk = Wtq + nw;
  unsigned short* Wtv = Wtk + nw;
  unsigned short* Wto = Wtv + nw;
  float*          opart = (float*)(Wto + nw);

  const size_t base_bytes = (nq * 2) * sizeof(float) +
                            (nk * 2 + nw * 4) * sizeof(unsigned short);
  const size_t per_split_bytes = (size_t)B_ * H_ * LQ_ * (D_ + 1) * sizeof(float);
  int S = 0;
  for (int cand = 16; cand >= 1; cand >>= 1) {
    if (base_bytes + (size_t)cand * per_split_bytes <= ws_size) { S = cand; break; }
  }

  wtrans4<<<dim3(16, 16, 4), 256, 0, stream>>>(Wq, Wk, Wv, Wo, Wtq, Wtk, Wtv, Wto);

  // Q proj: M=2048 -> 64 blocks; KV fused: M=20000 -> 625 blocks
  proj_wave<false, true><<<dim3(64), 256, 0, stream>>>(
      queries, Wtq, nullptr, bq, nullptr, qws, nullptr);
  proj_wave<true, false><<<dim3(625), 256, 0, stream>>>(
      bev, Wtk, Wtv, bk, bv, kbf, vbf);

  if (S <= 1) {
    attn_mfma<<<dim3(8, H_, B_), 256, 0, stream>>>(
        qws, kbf, vbf, nullptr, nullptr, ows, NT_, 1);
  } else {
    float* lpart = opart + (size_t)S * B_ * H_ * LQ_ * D_;
    const int tps = (NT_ + S - 1) / S;
    attn_mfma<<<dim3(8, H_, B_ * S), 256, 0, stream>>>(
        qws, kbf, vbf, opart, lpart, nullptr, tps, S);
    attn_merge<<<dim3((B_ * LQ_ * E_ + 255) / 256), 256, 0, stream>>>(
        opart, lpart, ows, S);
  }

  proj_wave<false, true><<<dim3(64), 256, 0, stream>>>(
      ows, Wto, nullptr, bo, nullptr, out, nullptr);
}

// Round 15
// 117.829 us; speedup vs baseline: 1.0348x; 1.0348x over previous
//
#include <hip/hip_runtime.h>
#include <hip/hip_bf16.h>

// Problem dims (fixed by reference)
#define B_  2
#define LQ_ 1024
#define LK_ 10000
#define E_  256
#define H_  8
#define D_  32
#define NT_ ((LK_ + 63) / 64)  // 157

typedef __attribute__((ext_vector_type(8))) short bf16x8;
typedef __attribute__((ext_vector_type(4))) short bf16x4;
typedef __attribute__((ext_vector_type(4))) float f32x4;

#define LOG2E 1.4426950408889634f

// float -> bf16 via native cast (compiler pairs into v_cvt_pk_bf16_f32)
static __device__ __forceinline__ short bfc(float x) {
  __bf16 b = (__bf16)x;
  return __builtin_bit_cast(short, b);
}
static __device__ __forceinline__ float bf2f(short s) {
  return (float)__builtin_bit_cast(__bf16, s);
}

// fast exp2 (v_exp_f32). NOTE: __exp2f collides with a glibc identifier.
#if __has_builtin(__builtin_amdgcn_exp2f)
static __device__ __forceinline__ float ex2(float x) {
  return __builtin_amdgcn_exp2f(x);
}
#else
static __device__ __forceinline__ float ex2(float x) { return exp2f(x); }
#endif

#if __has_builtin(__builtin_amdgcn_mfma_f32_16x16x16bf16_1k)
static __device__ __forceinline__ f32x4 mfma_pv(bf16x4 a, bf16x4 b, f32x4 c) {
  return __builtin_amdgcn_mfma_f32_16x16x16bf16_1k(a, b, c, 0, 0, 0);
}
#else
static __device__ __forceinline__ f32x4 mfma_pv(bf16x4 a, bf16x4 b, f32x4 c) {
  asm volatile("s_nop 1\n\tv_mfma_f32_16x16x16_bf16 %0, %1, %2, %0"
               : "+v"(c) : "v"(a), "v"(b));
  return c;
}
#endif

// Tile barrier WITHOUT vmcnt drain [T4]: cross-wave hazard at the tile
// boundary is LDS-only. Global prefetch loads only feed registers, so they
// stay in flight across the barrier (R12: +21 us vs __syncthreads).
static __device__ __forceinline__ void tile_barrier() {
  __builtin_amdgcn_sched_barrier(0);
  asm volatile("s_waitcnt lgkmcnt(0)" ::: "memory");
  __builtin_amdgcn_s_barrier();
  __builtin_amdgcn_sched_barrier(0);
}

// m204 bijective XCD-chunked swizzle
static __device__ __forceinline__ int xcd_swizzle(int flat, int nwg) {
  const int xcd = flat & 7, rest = flat >> 3;
  const int q = nwg >> 3, r = nwg & 7;
  return (xcd < r ? xcd * (q + 1) : r * (q + 1) + (xcd - r) * q) + rest;
}

// split f32x8 (two float4) into hi/lo bf16x8 planes
static __device__ __forceinline__ void split8(const float4& a, const float4& b,
                                              bf16x8& hi, bf16x8& lo) {
  float v[8] = {a.x, a.y, a.z, a.w, b.x, b.y, b.z, b.w};
#pragma unroll
  for (int i = 0; i < 8; ++i) {
    const short h = bfc(v[i]);
    hi[i] = h;
    lo[i] = bfc(v[i] - bf2f(h));
  }
}

// ---------------------------------------------------------------------------
// wtrans4: Wt_bf16[n][k] = bf16(W[k][n]) for 4 weights in one launch.
// ---------------------------------------------------------------------------
__global__ __launch_bounds__(256) void wtrans4(
    const float* __restrict__ W0, const float* __restrict__ W1,
    const float* __restrict__ W2, const float* __restrict__ W3,
    unsigned short* __restrict__ T0, unsigned short* __restrict__ T1,
    unsigned short* __restrict__ T2, unsigned short* __restrict__ T3) {
  const float* W;
  unsigned short* T;
  switch (blockIdx.z) {
    case 0:  W = W0; T = T0; break;
    case 1:  W = W1; T = T1; break;
    case 2:  W = W2; T = T2; break;
    default: W = W3; T = T3; break;
  }
  __shared__ float ts[16][17];
  const int tx = threadIdx.x & 15;
  const int ty = threadIdx.x >> 4;
  const int k0 = blockIdx.x * 16;
  const int n0 = blockIdx.y * 16;
  ts[ty][tx] = W[(size_t)(k0 + ty) * 256 + n0 + tx];
  __syncthreads();
  T[(size_t)(n0 + ty) * 256 + k0 + tx] = (unsigned short)bfc(ts[tx][ty]);
}

// ---------------------------------------------------------------------------
// proj_wave<KV,F32OUT>: barrier-free, LDS-free projection GEMM.
// Wave owns 32(m)x64(n). A from global f32, split hi/lo in regs, prefetched
// one kb ahead. W fragments now ALSO double-buffered in regs one kb ahead
// (R12 waited on W in-iteration: ~200cy L2 latency exposed per kb).
// mfma(W_frag, A_frag) -> D rows=n, cols=m -> vectorized stores.
// ---------------------------------------------------------------------------
template <bool KV, bool F32OUT>
__global__ __launch_bounds__(256) void proj_wave(
    const float* __restrict__ A,
    const unsigned short* __restrict__ Wt1,
    const unsigned short* __restrict__ Wt2,
    const float* __restrict__ b1, const float* __restrict__ b2,
    void* __restrict__ C1v, void* __restrict__ C2v) {
  const int lane = threadIdx.x & 63;
  const int nt   = threadIdx.x >> 6;   // wave id = n-tile (0..3)
  const int mt   = blockIdx.x;
  const int lr   = lane & 15;
  const int oc   = lane >> 4;          // k-octet (0..3)
  const int m0   = mt * 32;
  const int n0   = nt * 64;

  f32x4 ac1[2][4];
  f32x4 ac2[2][4];
#pragma unroll
  for (int s = 0; s < 2; ++s)
#pragma unroll
    for (int q = 0; q < 4; ++q) {
      ac1[s][q] = (f32x4){0.f, 0.f, 0.f, 0.f};
      if (KV) ac2[s][q] = (f32x4){0.f, 0.f, 0.f, 0.f};
    }

  const float* a0p = &A[(size_t)(m0 + lr) * 256 + oc * 8];
  const float* a1p = a0p + 16 * 256;

  // A regs for kb=0 (issued first)
  float4 c0a = *(const float4*)(a0p + 0);
  float4 c0b = *(const float4*)(a0p + 4);
  float4 c1a = *(const float4*)(a1p + 0);
  float4 c1b = *(const float4*)(a1p + 4);

  // W double-buffer; load kb=0 into bank 0
  bf16x8 w1b[2][4], w2b[2][4];
#pragma unroll
  for (int q = 0; q < 4; ++q) {
    w1b[0][q] = *(const bf16x8*)&Wt1[(size_t)(n0 + q * 16 + lr) * 256 + oc * 8];
    if (KV) w2b[0][q] = *(const bf16x8*)&Wt2[(size_t)(n0 + q * 16 + lr) * 256 + oc * 8];
  }

#pragma unroll
  for (int kb = 0; kb < 8; ++kb) {
    const int c = kb & 1;

    // convert current A (waits for A(kb); W(kb) issued earlier is also done)
    bf16x8 ah0, al0, ah1, al1;
    split8(c0a, c0b, ah0, al0);
    split8(c1a, c1b, ah1, al1);

    if (kb < 7) {
      // prefetch W(kb+1) into the other bank
      const size_t wko = (size_t)((kb + 1) * 32 + oc * 8);
#pragma unroll
      for (int q = 0; q < 4; ++q) {
        w1b[c ^ 1][q] = *(const bf16x8*)&Wt1[(size_t)(n0 + q * 16 + lr) * 256 + wko];
        if (KV) w2b[c ^ 1][q] = *(const bf16x8*)&Wt2[(size_t)(n0 + q * 16 + lr) * 256 + wko];
      }
      // prefetch A(kb+1) (ca/cb consumed by split8 above)
      c0a = *(const float4*)(a0p + (kb + 1) * 32 + 0);
      c0b = *(const float4*)(a0p + (kb + 1) * 32 + 4);
      c1a = *(const float4*)(a1p + (kb + 1) * 32 + 0);
      c1b = *(const float4*)(a1p + (kb + 1) * 32 + 4);
    }

#pragma unroll
    for (int q = 0; q < 4; ++q) {
      ac1[0][q] = __builtin_amdgcn_mfma_f32_16x16x32_bf16(w1b[c][q], ah0, ac1[0][q], 0, 0, 0);
      ac1[0][q] = __builtin_amdgcn_mfma_f32_16x16x32_bf16(w1b[c][q], al0, ac1[0][q], 0, 0, 0);
      ac1[1][q] = __builtin_amdgcn_mfma_f32_16x16x32_bf16(w1b[c][q], ah1, ac1[1][q], 0, 0, 0);
      ac1[1][q] = __builtin_amdgcn_mfma_f32_16x16x32_bf16(w1b[c][q], al1, ac1[1][q], 0, 0, 0);
      if (KV) {
        ac2[0][q] = __builtin_amdgcn_mfma_f32_16x16x32_bf16(w2b[c][q], ah0, ac2[0][q], 0, 0, 0);
        ac2[1][q] = __builtin_amdgcn_mfma_f32_16x16x32_bf16(w2b[c][q], ah1, ac2[1][q], 0, 0, 0);
      }
    }
  }

#pragma unroll
  for (int s = 0; s < 2; ++s) {
#pragma unroll
    for (int q = 0; q < 4; ++q) {
      const int m = m0 + s * 16 + lr;
      const int n = n0 + q * 16 + oc * 4;
      const float4 bv1 = *(const float4*)&b1[n];
      if (F32OUT) {
        float4 o;
        o.x = ac1[s][q][0] + bv1.x; o.y = ac1[s][q][1] + bv1.y;
        o.z = ac1[s][q][2] + bv1.z; o.w = ac1[s][q][3] + bv1.w;
        *(float4*)&((float*)C1v)[(size_t)m * 256 + n] = o;
      } else {
        ushort4 o;
        o.x = (unsigned short)bfc(ac1[s][q][0] + bv1.x);
        o.y = (unsigned short)bfc(ac1[s][q][1] + bv1.y);
        o.z = (unsigned short)bfc(ac1[s][q][2] + bv1.z);
        o.w = (unsigned short)bfc(ac1[s][q][3] + bv1.w);
        *(ushort4*)&((unsigned short*)C1v)[(size_t)m * 256 + n] = o;
      }
      if (KV) {
        const float4 bv2 = *(const float4*)&b2[n];
        ushort4 o;
        o.x = (unsigned short)bfc(ac2[s][q][0] + bv2.x);
        o.y = (unsigned short)bfc(ac2[s][q][1] + bv2.y);
        o.z = (unsigned short)bfc(ac2[s][q][2] + bv2.z);
        o.w = (unsigned short)bfc(ac2[s][q][3] + bv2.w);
        *(ushort4*)&((unsigned short*)C2v)[(size_t)m * 256 + n] = o;
      }
    }
  }
}

// ---------------------------------------------------------------------------
// attn_mfma: 128 q-rows/block, 32 q-rows/wave (two 16-row fragments A,B).
// Fixed-base softmax; l-accumulation in f32x4 (4x ILP); T4 lgkmcnt-only tile
// barrier; 2-phase LDS dbuf; split partials combine by plain sum.
// ---------------------------------------------------------------------------
__global__ __launch_bounds__(256, 4) void attn_mfma(const float* __restrict__ q,
                                                    const unsigned short* __restrict__ kbf,
                                                    const unsigned short* __restrict__ vbf,
                                                    float* __restrict__ Opart,
                                                    float* __restrict__ lpart,
                                                    float* __restrict__ o_direct,
                                                    int tiles_per_split, int nsplit) {
  const int nwg = 64 * gridDim.z;
  const int l   = xcd_swizzle(blockIdx.x + 8 * (blockIdx.y + 8 * blockIdx.z), nwg);
  const int qb   = l & 7;
  const int h    = (l >> 3) & 7;
  const int z    = l >> 6;
  const int s_id = z / B_;
  const int b    = z % B_;
  const int t    = threadIdx.x;
  const int lane = t & 63;
  const int w    = t >> 6;
  const int lq   = lane & 15;
  const int grp  = lane >> 4;

  __shared__ ushort Klds[2][64][64];
  __shared__ ushort Vtld[2][32][64];

  const int t0 = s_id * tiles_per_split;
  const int t1 = min(NT_, t0 + tiles_per_split);

  const int qrowA = qb * 128 + w * 32 + lq;  // fragment A rows
  const int qrowB = qrowA + 16;              // fragment B rows
  bf16x8 qfA, qfB;
  {
    const float* qpA = &q[((size_t)(b * LQ_ + qrowA)) * E_ + h * D_ + grp * 8];
    const float* qpB = &q[((size_t)(b * LQ_ + qrowB)) * E_ + h * D_ + grp * 8];
    const float4 a0 = *(const float4*)qpA;
    const float4 a1 = *(const float4*)(qpA + 4);
    const float4 b0 = *(const float4*)qpB;
    const float4 b1 = *(const float4*)(qpB + 4);
    qfA[0] = bfc(a0.x * LOG2E); qfA[1] = bfc(a0.y * LOG2E);
    qfA[2] = bfc(a0.z * LOG2E); qfA[3] = bfc(a0.w * LOG2E);
    qfA[4] = bfc(a1.x * LOG2E); qfA[5] = bfc(a1.y * LOG2E);
    qfA[6] = bfc(a1.z * LOG2E); qfA[7] = bfc(a1.w * LOG2E);
    qfB[0] = bfc(b0.x * LOG2E); qfB[1] = bfc(b0.y * LOG2E);
    qfB[2] = bfc(b0.z * LOG2E); qfB[3] = bfc(b0.w * LOG2E);
    qfB[4] = bfc(b1.x * LOG2E); qfB[5] = bfc(b1.y * LOG2E);
    qfB[6] = bfc(b1.z * LOG2E); qfB[7] = bfc(b1.w * LOG2E);
  }

  const int krow_l = t >> 2;
  const int kchunk = t & 3;
  const int vkp    = t >> 3;
  const int vd     = (t & 7) * 4;

  f32x4 lAv = {0.f, 0.f, 0.f, 0.f}, lBv = {0.f, 0.f, 0.f, 0.f};
  f32x4 a0A = {0.f, 0.f, 0.f, 0.f}, a1A = {0.f, 0.f, 0.f, 0.f};
  f32x4 a0B = {0.f, 0.f, 0.f, 0.f}, a1B = {0.f, 0.f, 0.f, 0.f};

  const size_t kvrow0 = (size_t)b * LK_;

  uint4 kval; ushort4 v0, v1;
  auto load_tile = [&](int kn) {
    if (kn == NT_ - 1) {
      const int krow  = min(kn * 64 + krow_l, LK_ - 1);
      const int vrow0 = min(kn * 64 + 2 * vkp, LK_ - 1);
      const int vrow1 = min(kn * 64 + 2 * vkp + 1, LK_ - 1);
      kval = *(const uint4*)&kbf[(kvrow0 + krow) * E_ + h * D_ + kchunk * 8];
      v0 = *(const ushort4*)&vbf[(kvrow0 + vrow0) * E_ + h * D_ + vd];
      v1 = *(const ushort4*)&vbf[(kvrow0 + vrow1) * E_ + h * D_ + vd];
    } else {
      kval = *(const uint4*)&kbf[(kvrow0 + kn * 64 + krow_l) * E_ + h * D_ + kchunk * 8];
      v0 = *(const ushort4*)&vbf[(kvrow0 + kn * 64 + 2 * vkp) * E_ + h * D_ + vd];
      v1 = *(const ushort4*)&vbf[(kvrow0 + kn * 64 + 2 * vkp + 1) * E_ + h * D_ + vd];
    }
  };
  auto store_tile = [&](int buf) {
    *(uint4*)((char*)&Klds[buf][krow_l][0] + ((kchunk * 16) ^ ((krow_l & 7) << 4))) = kval;
#pragma unroll
    for (int i = 0; i < 4; ++i) {
      const int d = vd + i;
      *(ushort2*)((char*)&Vtld[buf][d][0] + ((vkp * 4) ^ ((d & 7) << 4))) =
          make_ushort2(((const unsigned short*)&v0)[i], ((const unsigned short*)&v1)[i]);
    }
  };

  load_tile(t0);
  store_tile(0);
  if (t0 + 1 < t1) load_tile(t0 + 1);
  tile_barrier();

  int cur = 0;
  for (int kt = t0; kt < t1; ++kt) {
    const int rem = LK_ - kt * 64;

    if (kt + 1 < t1) store_tile(cur ^ 1);
    if (kt + 2 < t1) load_tile(kt + 2);

    // S^T = K · Q^T for both q-fragments (kf shared)
    f32x4 pA[4], pB[4];
    __builtin_amdgcn_s_setprio(1);
#pragma unroll
    for (int s = 0; s < 4; ++s) {
      const int row = s * 16 + lq;
      const bf16x8 kf = *(const bf16x8*)((const char*)&Klds[cur][row][0] +
                                         ((grp * 16) ^ ((row & 7) << 4)));
      const f32x4 zero = {0.f, 0.f, 0.f, 0.f};
      pA[s] = __builtin_amdgcn_mfma_f32_16x16x32_bf16(kf, qfA, zero, 0, 0, 0);
      pB[s] = __builtin_amdgcn_mfma_f32_16x16x32_bf16(kf, qfB, zero, 0, 0, 0);
    }
    __builtin_amdgcn_s_setprio(0);

    // fixed-base softmax: e = 2^s directly (q pre-scaled by log2e).
    // l accumulated per-r (f32x4) — independent add chains, 4x ILP.
    bf16x4 pbA[4], pbB[4];
    if (rem >= 64) {
#pragma unroll
      for (int s = 0; s < 4; ++s)
#pragma unroll
        for (int r = 0; r < 4; ++r) {
          const float eA = ex2(pA[s][r]);
          const float eB = ex2(pB[s][r]);
          lAv[r] += eA; lBv[r] += eB;
          pbA[s][r] = bfc(eA); pbB[s][r] = bfc(eB);
        }
    } else {
#pragma unroll
      for (int s = 0; s < 4; ++s) {
        const bool vs = (s * 16 + grp * 4) < rem;
#pragma unroll
        for (int r = 0; r < 4; ++r) {
          const float eA = vs ? ex2(pA[s][r]) : 0.f;
          const float eB = vs ? ex2(pB[s][r]) : 0.f;
          lAv[r] += eA; lBv[r] += eB;
          pbA[s][r] = bfc(eA); pbB[s][r] = bfc(eB);
        }
      }
    }

    // O^T += V^T · P for both fragments (vf shared)
    __builtin_amdgcn_s_setprio(1);
#pragma unroll
    for (int s = 0; s < 4; ++s) {
      {
        const int row = lq;
        const bf16x4 vf = *(const bf16x4*)((const char*)&Vtld[cur][row][0] +
                                           ((s * 32 + grp * 8) ^ ((row & 7) << 4)));
        a0A = mfma_pv(vf, pbA[s], a0A);
        a0B = mfma_pv(vf, pbB[s], a0B);
      }
      {
        const int row = 16 + lq;
        const bf16x4 vf = *(const bf16x4*)((const char*)&Vtld[cur][row][0] +
                                           ((s * 32 + grp * 8) ^ ((row & 7) << 4)));
        a1A = mfma_pv(vf, pbA[s], a1A);
        a1B = mfma_pv(vf, pbB[s], a1B);
      }
    }
    __builtin_amdgcn_s_setprio(0);

    tile_barrier();
    cur ^= 1;
  }

  float lA = (lAv[0] + lAv[1]) + (lAv[2] + lAv[3]);
  float lB = (lBv[0] + lBv[1]) + (lBv[2] + lBv[3]);
  lA += __shfl_xor(lA, 16);
  lA += __shfl_xor(lA, 32);
  lB += __shfl_xor(lB, 16);
  lB += __shfl_xor(lB, 32);

  if (nsplit == 1) {
    const float invA = 1.f / lA;
    const float invB = 1.f / lB;
    float* opA = &o_direct[((size_t)(b * LQ_ + qrowA)) * E_ + h * D_];
    float* opB = &o_direct[((size_t)(b * LQ_ + qrowB)) * E_ + h * D_];
#pragma unroll
    for (int r = 0; r < 4; ++r) {
      opA[grp * 4 + r]      = a0A[r] * invA;
      opA[16 + grp * 4 + r] = a1A[r] * invA;
      opB[grp * 4 + r]      = a0B[r] * invB;
      opB[16 + grp * 4 + r] = a1B[r] * invB;
    }
  } else {
    const size_t pbA =
        (size_t)s_id * (B_ * H_ * LQ_) + ((size_t)b * H_ + h) * LQ_ + qrowA;
    const size_t pbB = pbA + 16;
#pragma unroll
    for (int r = 0; r < 4; ++r) {
      Opart[pbA * D_ + grp * 4 + r]      = a0A[r];
      Opart[pbA * D_ + 16 + grp * 4 + r] = a1A[r];
      Opart[pbB * D_ + grp * 4 + r]      = a0B[r];
      Opart[pbB * D_ + 16 + grp * 4 + r] = a1B[r];
    }
    if (grp == 0) {
      lpart[pbA] = lA;
      lpart[pbB] = lB;
    }
  }
}

// ---------------------------------------------------------------------------
// attn_merge: absolute-scale partials combine by plain sum.
// ---------------------------------------------------------------------------
__global__ __launch_bounds__(256) void attn_merge(const float* __restrict__ Opart,
                                                  const float* __restrict__ lpart,
                                                  float* __restrict__ o, int S) {
  const int idx = blockIdx.x * 256 + threadIdx.x;
  if (idx >= B_ * LQ_ * E_) return;
  const int e   = idx & (E_ - 1);
  const int row = idx >> 8;
  const int b   = row >> 10;
  const int qq  = row & (LQ_ - 1);
  const int h   = e >> 5;
  const int d   = e & (D_ - 1);
  const size_t base   = ((size_t)b * H_ + h) * LQ_ + qq;
  const size_t stride = (size_t)B_ * H_ * LQ_;

  float lsum = 0.f, osum = 0.f;
  for (int s = 0; s < S; ++s) {
    lsum += lpart[s * stride + base];
    osum += Opart[(s * stride + base) * D_ + d];
  }
  o[idx] = osum / lsum;
}

// ---------------------------------------------------------------------------
extern "C" void kernel_launch(void* const* d_in, const int* in_sizes, int n_in,
                              void* d_out, int out_size, void* d_ws, size_t ws_size,
                              hipStream_t stream) {
  const float* bev     = (const float*)d_in[0];
  const float* queries = (const float*)d_in[1];
  const float* Wq      = (const float*)d_in[2];
  const float* bq      = (const float*)d_in[3];
  const float* Wk      = (const float*)d_in[4];
  const float* bk      = (const float*)d_in[5];
  const float* Wv      = (const float*)d_in[6];
  const float* bv      = (const float*)d_in[7];
  const float* Wo      = (const float*)d_in[8];
  const float* bo      = (const float*)d_in[9];
  float* out = (float*)d_out;

  // ws: q f32 | k bf16 | v bf16 | o f32 | Wtq|Wtk|Wtv|Wto bf16 | Opart | l
  const size_t nq = (size_t)B_ * LQ_ * E_;  // 524288
  const size_t nk = (size_t)B_ * LK_ * E_;  // 5120000
  const size_t nw = (size_t)E_ * E_;        // 65536
  float*          qws = (float*)d_ws;
  unsigned short* kbf = (unsigned short*)(qws + nq);
  unsigned short* vbf = kbf + nk;
  float*          ows = (float*)(vbf + nk);
  unsigned short* Wtq = (unsigned short*)(ows + nq);
  unsigned short* Wtk = Wtq + nw;
  unsigned short* Wtv = Wtk + nw;
  unsigned short* Wto = Wtv + nw;
  float*          opart = (float*)(Wto + nw);

  const size_t base_bytes = (nq * 2) * sizeof(float) +
                            (nk * 2 + nw * 4) * sizeof(unsigned short);
  const size_t per_split_bytes = (size_t)B_ * H_ * LQ_ * (D_ + 1) * sizeof(float);
  int S = 0;
  for (int cand = 8; cand >= 1; cand >>= 1) {
    if (base_bytes + (size_t)cand * per_split_bytes <= ws_size) { S = cand; break; }
  }

  wtrans4<<<dim3(16, 16, 4), 256, 0, stream>>>(Wq, Wk, Wv, Wo, Wtq, Wtk, Wtv, Wto);

  // Q proj: M=2048 -> 64 blocks; KV fused: M=20000 -> 625 blocks
  proj_wave<false, true><<<dim3(64), 256, 0, stream>>>(
      queries, Wtq, nullptr, bq, nullptr, qws, nullptr);
  proj_wave<true, false><<<dim3(625), 256, 0, stream>>>(
      bev, Wtk, Wtv, bk, bv, kbf, vbf);

  if (S <= 1) {
    attn_mfma<<<dim3(8, H_, B_), 256, 0, stream>>>(
        qws, kbf, vbf, nullptr, nullptr, ows, NT_, 1);
  } else {
    float* lpart = opart + (size_t)S * B_ * H_ * LQ_ * D_;
    const int tps = (NT_ + S - 1) / S;
    attn_mfma<<<dim3(8, H_, B_ * S), 256, 0, stream>>>(
        qws, kbf, vbf, opart, lpart, nullptr, tps, S);
    attn_merge<<<dim3((B_ * LQ_ * E_ + 255) / 256), 256, 0, stream>>>(
        opart, lpart, ows, S);
  }

  proj_wave<false, true><<<dim3(64), 256, 0, stream>>>(
      ows, Wto, nullptr, bo, nullptr, out, nullptr);
}

// Round 16
// 108.955 us; speedup vs baseline: 1.1191x; 1.0814x over previous
//
#include <hip/hip_runtime.h>
#include <hip/hip_bf16.h>

// Problem dims (fixed by reference)
#define B_  2
#define LQ_ 1024
#define LK_ 10000
#define E_  256
#define H_  8
#define D_  32
#define NT_ ((LK_ + 63) / 64)  // 157
#define KVBLKS_ 625            // 20000 / 32
#define QBLKS_  64             // 2048 / 32

typedef __attribute__((ext_vector_type(8))) short bf16x8;
typedef __attribute__((ext_vector_type(4))) short bf16x4;
typedef __attribute__((ext_vector_type(4))) float f32x4;

#define LOG2E 1.4426950408889634f

// float -> bf16 via native cast (compiler pairs into v_cvt_pk_bf16_f32)
static __device__ __forceinline__ short bfc(float x) {
  __bf16 b = (__bf16)x;
  return __builtin_bit_cast(short, b);
}
static __device__ __forceinline__ float bf2f(short s) {
  return (float)__builtin_bit_cast(__bf16, s);
}

// fast exp2 (v_exp_f32). NOTE: __exp2f collides with a glibc identifier.
#if __has_builtin(__builtin_amdgcn_exp2f)
static __device__ __forceinline__ float ex2(float x) {
  return __builtin_amdgcn_exp2f(x);
}
#else
static __device__ __forceinline__ float ex2(float x) { return exp2f(x); }
#endif

#if __has_builtin(__builtin_amdgcn_mfma_f32_16x16x16bf16_1k)
static __device__ __forceinline__ f32x4 mfma_pv(bf16x4 a, bf16x4 b, f32x4 c) {
  return __builtin_amdgcn_mfma_f32_16x16x16bf16_1k(a, b, c, 0, 0, 0);
}
#else
static __device__ __forceinline__ f32x4 mfma_pv(bf16x4 a, bf16x4 b, f32x4 c) {
  asm volatile("s_nop 1\n\tv_mfma_f32_16x16x16_bf16 %0, %1, %2, %0"
               : "+v"(c) : "v"(a), "v"(b));
  return c;
}
#endif

// Tile barrier WITHOUT vmcnt drain [T4]: cross-wave hazard at the tile
// boundary is LDS-only. Global prefetch loads only feed registers, so they
// stay in flight across the barrier (R12: +21 us vs __syncthreads).
static __device__ __forceinline__ void tile_barrier() {
  __builtin_amdgcn_sched_barrier(0);
  asm volatile("s_waitcnt lgkmcnt(0)" ::: "memory");
  __builtin_amdgcn_s_barrier();
  __builtin_amdgcn_sched_barrier(0);
}

// m204 bijective XCD-chunked swizzle
static __device__ __forceinline__ int xcd_swizzle(int flat, int nwg) {
  const int xcd = flat & 7, rest = flat >> 3;
  const int q = nwg >> 3, r = nwg & 7;
  return (xcd < r ? xcd * (q + 1) : r * (q + 1) + (xcd - r) * q) + rest;
}

// split f32x8 (two float4) into hi/lo bf16x8 planes
static __device__ __forceinline__ void split8(const float4& a, const float4& b,
                                              bf16x8& hi, bf16x8& lo) {
  float v[8] = {a.x, a.y, a.z, a.w, b.x, b.y, b.z, b.w};
#pragma unroll
  for (int i = 0; i < 8; ++i) {
    const short h = bfc(v[i]);
    hi[i] = h;
    lo[i] = bfc(v[i] - bf2f(h));
  }
}

// ---------------------------------------------------------------------------
// wtrans4: Wt_bf16[n][k] = bf16(W[k][n]) for 4 weights in one launch.
// ---------------------------------------------------------------------------
__global__ __launch_bounds__(256) void wtrans4(
    const float* __restrict__ W0, const float* __restrict__ W1,
    const float* __restrict__ W2, const float* __restrict__ W3,
    unsigned short* __restrict__ T0, unsigned short* __restrict__ T1,
    unsigned short* __restrict__ T2, unsigned short* __restrict__ T3) {
  const float* W;
  unsigned short* T;
  switch (blockIdx.z) {
    case 0:  W = W0; T = T0; break;
    case 1:  W = W1; T = T1; break;
    case 2:  W = W2; T = T2; break;
    default: W = W3; T = T3; break;
  }
  __shared__ float ts[16][17];
  const int tx = threadIdx.x & 15;
  const int ty = threadIdx.x >> 4;
  const int k0 = blockIdx.x * 16;
  const int n0 = blockIdx.y * 16;
  ts[ty][tx] = W[(size_t)(k0 + ty) * 256 + n0 + tx];
  __syncthreads();
  T[(size_t)(n0 + ty) * 256 + k0 + tx] = (unsigned short)bfc(ts[tx][ty]);
}

// ---------------------------------------------------------------------------
// proj_all: fused KV + Q projections, barrier-free, LDS-free, 32 rows/wave.
// Blocks [0,625): KV (bev -> K split-A hi/lo + V hi-only, bf16 out).
// Blocks [625,689): Q (queries -> qws, split-A, f32 out).
// DEPTH-2 A prefetch (two register banks, kb fully unrolled): A-load HBM
// latency (~900cy) is covered by 2 iterations of work across resident waves
// (R15's depth-1 covered only ~440cy -> stall; W-dbuf was neutral because
// W is L2-resident and already covered). W loads in-iteration (R12 style).
// ---------------------------------------------------------------------------
__global__ __launch_bounds__(256) void proj_all(
    const float* __restrict__ bev, const float* __restrict__ queries,
    const unsigned short* __restrict__ Wtk, const unsigned short* __restrict__ Wtv,
    const unsigned short* __restrict__ Wtq,
    const float* __restrict__ bk, const float* __restrict__ bv,
    const float* __restrict__ bq,
    unsigned short* __restrict__ kout, unsigned short* __restrict__ vout,
    float* __restrict__ qout) {
  const int lane = threadIdx.x & 63;
  const int nt   = threadIdx.x >> 6;   // wave id = n-tile (0..3)
  const int lr   = lane & 15;
  const int oc   = lane >> 4;          // k-octet (0..3)
  const int n0   = nt * 64;

  const bool isQ = (blockIdx.x >= KVBLKS_);
  const int  m0  = (isQ ? (int)blockIdx.x - KVBLKS_ : (int)blockIdx.x) * 32;
  const float* A = isQ ? queries : bev;
  const unsigned short* W1 = isQ ? Wtq : Wtk;

  f32x4 ac1[2][4], ac2[2][4];
#pragma unroll
  for (int s = 0; s < 2; ++s)
#pragma unroll
    for (int q = 0; q < 4; ++q) {
      ac1[s][q] = (f32x4){0.f, 0.f, 0.f, 0.f};
      ac2[s][q] = (f32x4){0.f, 0.f, 0.f, 0.f};
    }

  const float* a0p = &A[(size_t)(m0 + lr) * 256 + oc * 8];
  const float* a1p = a0p + 16 * 256;

  // depth-2 A prefetch: bank[kb&1] holds A(kb); prologue fills A(0), A(1)
  float4 ab[2][4];
  ab[0][0] = *(const float4*)(a0p + 0);
  ab[0][1] = *(const float4*)(a0p + 4);
  ab[0][2] = *(const float4*)(a1p + 0);
  ab[0][3] = *(const float4*)(a1p + 4);
  ab[1][0] = *(const float4*)(a0p + 32);
  ab[1][1] = *(const float4*)(a0p + 36);
  ab[1][2] = *(const float4*)(a1p + 32);
  ab[1][3] = *(const float4*)(a1p + 36);

#pragma unroll
  for (int kb = 0; kb < 8; ++kb) {
    const int bk_ = kb & 1;

    // W(kb) fragments (L2-hot); issued before split8 so their latency
    // overlaps the cvt VALU work
    const int wko = kb * 32 + oc * 8;
    bf16x8 w1[4], w2[4];
#pragma unroll
    for (int q = 0; q < 4; ++q) {
      w1[q] = *(const bf16x8*)&W1[(size_t)(n0 + q * 16 + lr) * 256 + wko];
      if (!isQ) w2[q] = *(const bf16x8*)&Wtv[(size_t)(n0 + q * 16 + lr) * 256 + wko];
    }

    // convert A(kb) (waits only on loads issued 2 iterations ago)
    bf16x8 ah0, al0, ah1, al1;
    split8(ab[bk_][0], ab[bk_][1], ah0, al0);
    split8(ab[bk_][2], ab[bk_][3], ah1, al1);

    // refill freed bank with A(kb+2)
    if (kb < 6) {
      ab[bk_][0] = *(const float4*)(a0p + (kb + 2) * 32 + 0);
      ab[bk_][1] = *(const float4*)(a0p + (kb + 2) * 32 + 4);
      ab[bk_][2] = *(const float4*)(a1p + (kb + 2) * 32 + 0);
      ab[bk_][3] = *(const float4*)(a1p + (kb + 2) * 32 + 4);
    }

#pragma unroll
    for (int q = 0; q < 4; ++q) {
      ac1[0][q] = __builtin_amdgcn_mfma_f32_16x16x32_bf16(w1[q], ah0, ac1[0][q], 0, 0, 0);
      ac1[0][q] = __builtin_amdgcn_mfma_f32_16x16x32_bf16(w1[q], al0, ac1[0][q], 0, 0, 0);
      ac1[1][q] = __builtin_amdgcn_mfma_f32_16x16x32_bf16(w1[q], ah1, ac1[1][q], 0, 0, 0);
      ac1[1][q] = __builtin_amdgcn_mfma_f32_16x16x32_bf16(w1[q], al1, ac1[1][q], 0, 0, 0);
      if (!isQ) {
        ac2[0][q] = __builtin_amdgcn_mfma_f32_16x16x32_bf16(w2[q], ah0, ac2[0][q], 0, 0, 0);
        ac2[1][q] = __builtin_amdgcn_mfma_f32_16x16x32_bf16(w2[q], ah1, ac2[1][q], 0, 0, 0);
      }
    }
  }

  // epilogue: m = m0+s*16+lr, n = n0+q*16+oc*4+(0..3)
#pragma unroll
  for (int s = 0; s < 2; ++s) {
#pragma unroll
    for (int q = 0; q < 4; ++q) {
      const int m = m0 + s * 16 + lr;
      const int n = n0 + q * 16 + oc * 4;
      if (isQ) {
        const float4 b4 = *(const float4*)&bq[n];
        float4 o;
        o.x = ac1[s][q][0] + b4.x; o.y = ac1[s][q][1] + b4.y;
        o.z = ac1[s][q][2] + b4.z; o.w = ac1[s][q][3] + b4.w;
        *(float4*)&qout[(size_t)m * 256 + n] = o;
      } else {
        const float4 bk4 = *(const float4*)&bk[n];
        const float4 bv4 = *(const float4*)&bv[n];
        ushort4 ok, ov;
        ok.x = (unsigned short)bfc(ac1[s][q][0] + bk4.x);
        ok.y = (unsigned short)bfc(ac1[s][q][1] + bk4.y);
        ok.z = (unsigned short)bfc(ac1[s][q][2] + bk4.z);
        ok.w = (unsigned short)bfc(ac1[s][q][3] + bk4.w);
        ov.x = (unsigned short)bfc(ac2[s][q][0] + bv4.x);
        ov.y = (unsigned short)bfc(ac2[s][q][1] + bv4.y);
        ov.z = (unsigned short)bfc(ac2[s][q][2] + bv4.z);
        ov.w = (unsigned short)bfc(ac2[s][q][3] + bv4.w);
        *(ushort4*)&kout[(size_t)m * 256 + n] = ok;
        *(ushort4*)&vout[(size_t)m * 256 + n] = ov;
      }
    }
  }
}

// ---------------------------------------------------------------------------
// proj_o: O-projection (split-A, f32 out), 32 rows/wave, depth-2 A prefetch.
// ---------------------------------------------------------------------------
__global__ __launch_bounds__(256) void proj_o(const float* __restrict__ A,
                                              const unsigned short* __restrict__ Wt,
                                              const float* __restrict__ bias,
                                              float* __restrict__ C) {
  const int lane = threadIdx.x & 63;
  const int nt   = threadIdx.x >> 6;
  const int lr   = lane & 15;
  const int oc   = lane >> 4;
  const int n0   = nt * 64;
  const int m0   = blockIdx.x * 32;

  f32x4 acc[2][4];
#pragma unroll
  for (int s = 0; s < 2; ++s)
#pragma unroll
    for (int q = 0; q < 4; ++q) acc[s][q] = (f32x4){0.f, 0.f, 0.f, 0.f};

  const float* a0p = &A[(size_t)(m0 + lr) * 256 + oc * 8];
  const float* a1p = a0p + 16 * 256;

  float4 ab[2][4];
  ab[0][0] = *(const float4*)(a0p + 0);
  ab[0][1] = *(const float4*)(a0p + 4);
  ab[0][2] = *(const float4*)(a1p + 0);
  ab[0][3] = *(const float4*)(a1p + 4);
  ab[1][0] = *(const float4*)(a0p + 32);
  ab[1][1] = *(const float4*)(a0p + 36);
  ab[1][2] = *(const float4*)(a1p + 32);
  ab[1][3] = *(const float4*)(a1p + 36);

#pragma unroll
  for (int kb = 0; kb < 8; ++kb) {
    const int bk_ = kb & 1;
    const int wko = kb * 32 + oc * 8;
    bf16x8 w[4];
#pragma unroll
    for (int q = 0; q < 4; ++q)
      w[q] = *(const bf16x8*)&Wt[(size_t)(n0 + q * 16 + lr) * 256 + wko];

    bf16x8 ah0, al0, ah1, al1;
    split8(ab[bk_][0], ab[bk_][1], ah0, al0);
    split8(ab[bk_][2], ab[bk_][3], ah1, al1);

    if (kb < 6) {
      ab[bk_][0] = *(const float4*)(a0p + (kb + 2) * 32 + 0);
      ab[bk_][1] = *(const float4*)(a0p + (kb + 2) * 32 + 4);
      ab[bk_][2] = *(const float4*)(a1p + (kb + 2) * 32 + 0);
      ab[bk_][3] = *(const float4*)(a1p + (kb + 2) * 32 + 4);
    }

#pragma unroll
    for (int q = 0; q < 4; ++q) {
      acc[0][q] = __builtin_amdgcn_mfma_f32_16x16x32_bf16(w[q], ah0, acc[0][q], 0, 0, 0);
      acc[0][q] = __builtin_amdgcn_mfma_f32_16x16x32_bf16(w[q], al0, acc[0][q], 0, 0, 0);
      acc[1][q] = __builtin_amdgcn_mfma_f32_16x16x32_bf16(w[q], ah1, acc[1][q], 0, 0, 0);
      acc[1][q] = __builtin_amdgcn_mfma_f32_16x16x32_bf16(w[q], al1, acc[1][q], 0, 0, 0);
    }
  }

#pragma unroll
  for (int s = 0; s < 2; ++s) {
#pragma unroll
    for (int q = 0; q < 4; ++q) {
      const int m = m0 + s * 16 + lr;
      const int n = n0 + q * 16 + oc * 4;
      const float4 b4 = *(const float4*)&bias[n];
      float4 o;
      o.x = acc[s][q][0] + b4.x; o.y = acc[s][q][1] + b4.y;
      o.z = acc[s][q][2] + b4.z; o.w = acc[s][q][3] + b4.w;
      *(float4*)&C[(size_t)m * 256 + n] = o;
    }
  }
}

// ---------------------------------------------------------------------------
// attn_mfma: unchanged from R15 (128 q/block, 32 q/wave, fixed-base softmax,
// f32x4 l-accum, T4 lgkmcnt-only tile barrier, 2-phase LDS dbuf, S=8).
// ---------------------------------------------------------------------------
__global__ __launch_bounds__(256, 4) void attn_mfma(const float* __restrict__ q,
                                                    const unsigned short* __restrict__ kbf,
                                                    const unsigned short* __restrict__ vbf,
                                                    float* __restrict__ Opart,
                                                    float* __restrict__ lpart,
                                                    float* __restrict__ o_direct,
                                                    int tiles_per_split, int nsplit) {
  const int nwg = 64 * gridDim.z;
  const int l   = xcd_swizzle(blockIdx.x + 8 * (blockIdx.y + 8 * blockIdx.z), nwg);
  const int qb   = l & 7;
  const int h    = (l >> 3) & 7;
  const int z    = l >> 6;
  const int s_id = z / B_;
  const int b    = z % B_;
  const int t    = threadIdx.x;
  const int lane = t & 63;
  const int w    = t >> 6;
  const int lq   = lane & 15;
  const int grp  = lane >> 4;

  __shared__ ushort Klds[2][64][64];
  __shared__ ushort Vtld[2][32][64];

  const int t0 = s_id * tiles_per_split;
  const int t1 = min(NT_, t0 + tiles_per_split);

  const int qrowA = qb * 128 + w * 32 + lq;
  const int qrowB = qrowA + 16;
  bf16x8 qfA, qfB;
  {
    const float* qpA = &q[((size_t)(b * LQ_ + qrowA)) * E_ + h * D_ + grp * 8];
    const float* qpB = &q[((size_t)(b * LQ_ + qrowB)) * E_ + h * D_ + grp * 8];
    const float4 a0 = *(const float4*)qpA;
    const float4 a1 = *(const float4*)(qpA + 4);
    const float4 b0 = *(const float4*)qpB;
    const float4 b1 = *(const float4*)(qpB + 4);
    qfA[0] = bfc(a0.x * LOG2E); qfA[1] = bfc(a0.y * LOG2E);
    qfA[2] = bfc(a0.z * LOG2E); qfA[3] = bfc(a0.w * LOG2E);
    qfA[4] = bfc(a1.x * LOG2E); qfA[5] = bfc(a1.y * LOG2E);
    qfA[6] = bfc(a1.z * LOG2E); qfA[7] = bfc(a1.w * LOG2E);
    qfB[0] = bfc(b0.x * LOG2E); qfB[1] = bfc(b0.y * LOG2E);
    qfB[2] = bfc(b0.z * LOG2E); qfB[3] = bfc(b0.w * LOG2E);
    qfB[4] = bfc(b1.x * LOG2E); qfB[5] = bfc(b1.y * LOG2E);
    qfB[6] = bfc(b1.z * LOG2E); qfB[7] = bfc(b1.w * LOG2E);
  }

  const int krow_l = t >> 2;
  const int kchunk = t & 3;
  const int vkp    = t >> 3;
  const int vd     = (t & 7) * 4;

  f32x4 lAv = {0.f, 0.f, 0.f, 0.f}, lBv = {0.f, 0.f, 0.f, 0.f};
  f32x4 a0A = {0.f, 0.f, 0.f, 0.f}, a1A = {0.f, 0.f, 0.f, 0.f};
  f32x4 a0B = {0.f, 0.f, 0.f, 0.f}, a1B = {0.f, 0.f, 0.f, 0.f};

  const size_t kvrow0 = (size_t)b * LK_;

  uint4 kval; ushort4 v0, v1;
  auto load_tile = [&](int kn) {
    if (kn == NT_ - 1) {
      const int krow  = min(kn * 64 + krow_l, LK_ - 1);
      const int vrow0 = min(kn * 64 + 2 * vkp, LK_ - 1);
      const int vrow1 = min(kn * 64 + 2 * vkp + 1, LK_ - 1);
      kval = *(const uint4*)&kbf[(kvrow0 + krow) * E_ + h * D_ + kchunk * 8];
      v0 = *(const ushort4*)&vbf[(kvrow0 + vrow0) * E_ + h * D_ + vd];
      v1 = *(const ushort4*)&vbf[(kvrow0 + vrow1) * E_ + h * D_ + vd];
    } else {
      kval = *(const uint4*)&kbf[(kvrow0 + kn * 64 + krow_l) * E_ + h * D_ + kchunk * 8];
      v0 = *(const ushort4*)&vbf[(kvrow0 + kn * 64 + 2 * vkp) * E_ + h * D_ + vd];
      v1 = *(const ushort4*)&vbf[(kvrow0 + kn * 64 + 2 * vkp + 1) * E_ + h * D_ + vd];
    }
  };
  auto store_tile = [&](int buf) {
    *(uint4*)((char*)&Klds[buf][krow_l][0] + ((kchunk * 16) ^ ((krow_l & 7) << 4))) = kval;
#pragma unroll
    for (int i = 0; i < 4; ++i) {
      const int d = vd + i;
      *(ushort2*)((char*)&Vtld[buf][d][0] + ((vkp * 4) ^ ((d & 7) << 4))) =
          make_ushort2(((const unsigned short*)&v0)[i], ((const unsigned short*)&v1)[i]);
    }
  };

  load_tile(t0);
  store_tile(0);
  if (t0 + 1 < t1) load_tile(t0 + 1);
  tile_barrier();

  int cur = 0;
  for (int kt = t0; kt < t1; ++kt) {
    const int rem = LK_ - kt * 64;

    if (kt + 1 < t1) store_tile(cur ^ 1);
    if (kt + 2 < t1) load_tile(kt + 2);

    f32x4 pA[4], pB[4];
    __builtin_amdgcn_s_setprio(1);
#pragma unroll
    for (int s = 0; s < 4; ++s) {
      const int row = s * 16 + lq;
      const bf16x8 kf = *(const bf16x8*)((const char*)&Klds[cur][row][0] +
                                         ((grp * 16) ^ ((row & 7) << 4)));
      const f32x4 zero = {0.f, 0.f, 0.f, 0.f};
      pA[s] = __builtin_amdgcn_mfma_f32_16x16x32_bf16(kf, qfA, zero, 0, 0, 0);
      pB[s] = __builtin_amdgcn_mfma_f32_16x16x32_bf16(kf, qfB, zero, 0, 0, 0);
    }
    __builtin_amdgcn_s_setprio(0);

    bf16x4 pbA[4], pbB[4];
    if (rem >= 64) {
#pragma unroll
      for (int s = 0; s < 4; ++s)
#pragma unroll
        for (int r = 0; r < 4; ++r) {
          const float eA = ex2(pA[s][r]);
          const float eB = ex2(pB[s][r]);
          lAv[r] += eA; lBv[r] += eB;
          pbA[s][r] = bfc(eA); pbB[s][r] = bfc(eB);
        }
    } else {
#pragma unroll
      for (int s = 0; s < 4; ++s) {
        const bool vs = (s * 16 + grp * 4) < rem;
#pragma unroll
        for (int r = 0; r < 4; ++r) {
          const float eA = vs ? ex2(pA[s][r]) : 0.f;
          const float eB = vs ? ex2(pB[s][r]) : 0.f;
          lAv[r] += eA; lBv[r] += eB;
          pbA[s][r] = bfc(eA); pbB[s][r] = bfc(eB);
        }
      }
    }

    __builtin_amdgcn_s_setprio(1);
#pragma unroll
    for (int s = 0; s < 4; ++s) {
      {
        const int row = lq;
        const bf16x4 vf = *(const bf16x4*)((const char*)&Vtld[cur][row][0] +
                                           ((s * 32 + grp * 8) ^ ((row & 7) << 4)));
        a0A = mfma_pv(vf, pbA[s], a0A);
        a0B = mfma_pv(vf, pbB[s], a0B);
      }
      {
        const int row = 16 + lq;
        const bf16x4 vf = *(const bf16x4*)((const char*)&Vtld[cur][row][0] +
                                           ((s * 32 + grp * 8) ^ ((row & 7) << 4)));
        a1A = mfma_pv(vf, pbA[s], a1A);
        a1B = mfma_pv(vf, pbB[s], a1B);
      }
    }
    __builtin_amdgcn_s_setprio(0);

    tile_barrier();
    cur ^= 1;
  }

  float lA = (lAv[0] + lAv[1]) + (lAv[2] + lAv[3]);
  float lB = (lBv[0] + lBv[1]) + (lBv[2] + lBv[3]);
  lA += __shfl_xor(lA, 16);
  lA += __shfl_xor(lA, 32);
  lB += __shfl_xor(lB, 16);
  lB += __shfl_xor(lB, 32);

  if (nsplit == 1) {
    const float invA = 1.f / lA;
    const float invB = 1.f / lB;
    float* opA = &o_direct[((size_t)(b * LQ_ + qrowA)) * E_ + h * D_];
    float* opB = &o_direct[((size_t)(b * LQ_ + qrowB)) * E_ + h * D_];
#pragma unroll
    for (int r = 0; r < 4; ++r) {
      opA[grp * 4 + r]      = a0A[r] * invA;
      opA[16 + grp * 4 + r] = a1A[r] * invA;
      opB[grp * 4 + r]      = a0B[r] * invB;
      opB[16 + grp * 4 + r] = a1B[r] * invB;
    }
  } else {
    const size_t pbA =
        (size_t)s_id * (B_ * H_ * LQ_) + ((size_t)b * H_ + h) * LQ_ + qrowA;
    const size_t pbB = pbA + 16;
#pragma unroll
    for (int r = 0; r < 4; ++r) {
      Opart[pbA * D_ + grp * 4 + r]      = a0A[r];
      Opart[pbA * D_ + 16 + grp * 4 + r] = a1A[r];
      Opart[pbB * D_ + grp * 4 + r]      = a0B[r];
      Opart[pbB * D_ + 16 + grp * 4 + r] = a1B[r];
    }
    if (grp == 0) {
      lpart[pbA] = lA;
      lpart[pbB] = lB;
    }
  }
}

// ---------------------------------------------------------------------------
// attn_merge: absolute-scale partials combine by plain sum.
// ---------------------------------------------------------------------------
__global__ __launch_bounds__(256) void attn_merge(const float* __restrict__ Opart,
                                                  const float* __restrict__ lpart,
                                                  float* __restrict__ o, int S) {
  const int idx = blockIdx.x * 256 + threadIdx.x;
  if (idx >= B_ * LQ_ * E_) return;
  const int e   = idx & (E_ - 1);
  const int row = idx >> 8;
  const int b   = row >> 10;
  const int qq  = row & (LQ_ - 1);
  const int h   = e >> 5;
  const int d   = e & (D_ - 1);
  const size_t base   = ((size_t)b * H_ + h) * LQ_ + qq;
  const size_t stride = (size_t)B_ * H_ * LQ_;

  float lsum = 0.f, osum = 0.f;
  for (int s = 0; s < S; ++s) {
    lsum += lpart[s * stride + base];
    osum += Opart[(s * stride + base) * D_ + d];
  }
  o[idx] = osum / lsum;
}

// ---------------------------------------------------------------------------
extern "C" void kernel_launch(void* const* d_in, const int* in_sizes, int n_in,
                              void* d_out, int out_size, void* d_ws, size_t ws_size,
                              hipStream_t stream) {
  const float* bev     = (const float*)d_in[0];
  const float* queries = (const float*)d_in[1];
  const float* Wq      = (const float*)d_in[2];
  const float* bq      = (const float*)d_in[3];
  const float* Wk      = (const float*)d_in[4];
  const float* bk      = (const float*)d_in[5];
  const float* Wv      = (const float*)d_in[6];
  const float* bv      = (const float*)d_in[7];
  const float* Wo      = (const float*)d_in[8];
  const float* bo      = (const float*)d_in[9];
  float* out = (float*)d_out;

  // ws: q f32 | k bf16 | v bf16 | o f32 | Wtq|Wtk|Wtv|Wto bf16 | Opart | l
  const size_t nq = (size_t)B_ * LQ_ * E_;  // 524288
  const size_t nk = (size_t)B_ * LK_ * E_;  // 5120000
  const size_t nw = (size_t)E_ * E_;        // 65536
  float*          qws = (float*)d_ws;
  unsigned short* kbf = (unsigned short*)(qws + nq);
  unsigned short* vbf = kbf + nk;
  float*          ows = (float*)(vbf + nk);
  unsigned short* Wtq = (unsigned short*)(ows + nq);
  unsigned short* Wtk = Wtq + nw;
  unsigned short* Wtv = Wtk + nw;
  unsigned short* Wto = Wtv + nw;
  float*          opart = (float*)(Wto + nw);

  const size_t base_bytes = (nq * 2) * sizeof(float) +
                            (nk * 2 + nw * 4) * sizeof(unsigned short);
  const size_t per_split_bytes = (size_t)B_ * H_ * LQ_ * (D_ + 1) * sizeof(float);
  int S = 0;
  for (int cand = 8; cand >= 1; cand >>= 1) {
    if (base_bytes + (size_t)cand * per_split_bytes <= ws_size) { S = cand; break; }
  }

  wtrans4<<<dim3(16, 16, 4), 256, 0, stream>>>(Wq, Wk, Wv, Wo, Wtq, Wtk, Wtv, Wto);

  // fused: KV (blocks 0..624) + Q (blocks 625..688)
  proj_all<<<dim3(KVBLKS_ + QBLKS_), 256, 0, stream>>>(
      bev, queries, Wtk, Wtv, Wtq, bk, bv, bq, kbf, vbf, qws);

  if (S <= 1) {
    attn_mfma<<<dim3(8, H_, B_), 256, 0, stream>>>(
        qws, kbf, vbf, nullptr, nullptr, ows, NT_, 1);
  } else {
    float* lpart = opart + (size_t)S * B_ * H_ * LQ_ * D_;
    const int tps = (NT_ + S - 1) / S;
    attn_mfma<<<dim3(8, H_, B_ * S), 256, 0, stream>>>(
        qws, kbf, vbf, opart, lpart, nullptr, tps, S);
    attn_merge<<<dim3((B_ * LQ_ * E_ + 255) / 256), 256, 0, stream>>>(
        opart, lpart, ows, S);
  }

  proj_o<<<dim3(QBLKS_), 256, 0, stream>>>(ows, Wto, bo, out);
}